// Round 3
// baseline (1121.443 us; speedup 1.0000x reference)
//
#include <hip/hip_runtime.h>

#define B_ 256
#define T_ 1024
#define E_ 32
#define H_ 128
#define NOBS_ 1048576
#define RPB 4                 // batch rows per LSTM block
#define NBLK (B_ / RPB)       // 64
#define NW 8                  // waves per block
#define THREADS (NW * 64)     // 512

#define LROWH 136             // h row length in bf16 (128 + 8 pad) -> 272B row stride
#define HBUF (4 * LROWH)      // one h buffer (4 rows), in shorts

typedef __attribute__((ext_vector_type(8))) short bf16x8;
typedef __attribute__((ext_vector_type(4))) float f32x4;

// LDS-only barrier: drains LDS ops only; global loads/stores stay in flight.
#define LDS_BARRIER() asm volatile("s_waitcnt lgkmcnt(0)\n\ts_barrier" ::: "memory")

__device__ __forceinline__ short f2bf(float x) {
    unsigned u = __float_as_uint(x);
    unsigned r = u + 0x7FFFu + ((u >> 16) & 1u);   // round-to-nearest-even
    return (short)(r >> 16);
}

__device__ __forceinline__ float fast_sigmoid(float x) {
    float e = __expf(-x);
    return __builtin_amdgcn_rcpf(1.0f + e);
}

__device__ __forceinline__ float fast_tanh(float x) {
    float e = __expf(2.0f * x);                    // inf for big x -> rcp=0 -> 1.0
    return 1.0f - 2.0f * __builtin_amdgcn_rcpf(e + 1.0f);
}

// ---------------- embedding kernel ----------------
__global__ void embed_kernel(const int* __restrict__ obs_ids,
                             const int* __restrict__ obs_slot,
                             const int* __restrict__ action_ids,
                             const int* __restrict__ is_action,
                             const float* __restrict__ action_emb,
                             const float* __restrict__ obs_emb,
                             float* __restrict__ embedded) {
    __shared__ float s_act[5 * E_];
    __shared__ float s_obs[11 * E_];
    for (int i = threadIdx.x; i < 5 * E_; i += blockDim.x) s_act[i] = action_emb[i];
    for (int i = threadIdx.x; i < 11 * E_; i += blockDim.x) s_obs[i] = obs_emb[i];
    __syncthreads();

    int s = blockIdx.x * blockDim.x + threadIdx.x;
    if (s >= B_ * T_) return;

    float acc[E_];
    if (is_action[s]) {
        int a = action_ids[s];
        #pragma unroll
        for (int e = 0; e < E_; e++) acc[e] = s_act[a * E_ + e];
    } else {
        #pragma unroll
        for (int e = 0; e < E_; e++) acc[e] = 0.0f;
        int lo = 0, hi = NOBS_;
        while (lo < hi) {
            int mid = (lo + hi) >> 1;
            if (obs_slot[mid] < s) lo = mid + 1; else hi = mid;
        }
        int j = lo;
        while (j < NOBS_ && obs_slot[j] == s) {
            int id = obs_ids[j];
            #pragma unroll
            for (int e = 0; e < E_; e++) acc[e] += s_obs[id * E_ + e];
            j++;
        }
    }
    float4* dst = (float4*)(embedded + (size_t)s * E_);
    #pragma unroll
    for (int q = 0; q < E_ / 4; q++) {
        float4 v; v.x = acc[4*q]; v.y = acc[4*q+1]; v.z = acc[4*q+2]; v.w = acc[4*q+3];
        dst[q] = v;
    }
}

// ---------------- LSTM kernel ----------------
// 8 waves, RPB=4 rows/block. Wave w owns h-cols [16w,16w+16). Elementwise runs
// in MFMA C-layout (lanes 16-63 are duplicates of lanes 0-15 because A rows
// 4-15 duplicate rows 0-3). Gates never touch LDS; only the 4x128 bf16 h tile
// bounces through a double-buffered LDS region with ONE lgkm barrier per step.
__launch_bounds__(THREADS, 2)
__global__ void lstm_kernel(const float* __restrict__ embedded,
                            const int* __restrict__ lengths,
                            const float* __restrict__ W_ih,
                            const float* __restrict__ W_hh,
                            const float* __restrict__ b_ih,
                            const float* __restrict__ b_hh,
                            float* __restrict__ outputs,
                            float* __restrict__ h_out,
                            float* __restrict__ c_out) {
    __shared__ __align__(16) short h_lds[2 * HBUF];   // double-buffered [4][LROWH]

    const int tid  = threadIdx.x;
    const int lane = tid & 63;
    const int wave = tid >> 6;
    const int row0 = blockIdx.x * RPB;

    const int col16 = (wave << 4) + (lane & 15);   // output h-col this lane owns
    const int kgrp  = (lane >> 4) * 8;             // k-slice within tile
    const int arow  = lane & 3;                    // A row (dup for lane&15 > 3)

    // ---- persistent weight fragments (B operand) ----
    bf16x8 wfrag[4][5];
    #pragma unroll
    for (int gt = 0; gt < 4; gt++) {
        int gcol = gt * H_ + col16;
        {
            const float* p = W_ih + (size_t)gcol * E_ + kgrp;
            bf16x8 v;
            #pragma unroll
            for (int j = 0; j < 8; j++) v[j] = f2bf(p[j]);
            wfrag[gt][0] = v;
        }
        #pragma unroll
        for (int kt = 1; kt < 5; kt++) {
            const float* q = W_hh + (size_t)gcol * H_ + (kt - 1) * 32 + kgrp;
            bf16x8 v;
            #pragma unroll
            for (int j = 0; j < 8; j++) v[j] = f2bf(q[j]);
            wfrag[gt][kt] = v;
        }
    }

    // per-lane biases for its column
    const float bias0 = b_ih[0 * H_ + col16] + b_hh[0 * H_ + col16];
    const float bias1 = b_ih[1 * H_ + col16] + b_hh[1 * H_ + col16];
    const float bias2 = b_ih[2 * H_ + col16] + b_hh[2 * H_ + col16];
    const float bias3 = b_ih[3 * H_ + col16] + b_hh[3 * H_ + col16];

    // uniform per-row lengths
    const int len0 = lengths[row0 + 0];
    const int len1 = lengths[row0 + 1];
    const int len2 = lengths[row0 + 2];
    const int len3 = lengths[row0 + 3];

    // c/h state per reg (rows 0-3), duplicated across lane groups
    float cr[4] = {0.f, 0.f, 0.f, 0.f};
    float hr[4] = {0.f, 0.f, 0.f, 0.f};

    // x fragment source: 8 consecutive floats at row (row0+arow), k = kgrp..kgrp+7
    const float* xp = embedded + ((size_t)(row0 + arow) * T_) * E_ + kgrp;

    // zero both h buffers
    for (int i = tid; i < 2 * HBUF; i += THREADS) h_lds[i] = 0;
    __syncthreads();

    // preload x(0)
    float4 xlo = *(const float4*)(xp + 0);
    float4 xhi = *(const float4*)(xp + 4);

    int rsel = 0;                                   // read-buffer offset (shorts)
    const int rbase = arow * LROWH + kgrp;          // + kt*32 + rsel
    const int wbase = col16;                        // + r*LROWH + wsel

    float* const out_base = outputs + (size_t)row0 * T_ * H_ + col16;
    const size_t row_stride = (size_t)T_ * H_;

    for (int t = 0; t < T_; ++t) {
        // convert prefetched x -> A fragment (vmcnt wait lands here)
        bf16x8 xa;
        xa[0] = f2bf(xlo.x); xa[1] = f2bf(xlo.y); xa[2] = f2bf(xlo.z); xa[3] = f2bf(xlo.w);
        xa[4] = f2bf(xhi.x); xa[5] = f2bf(xhi.y); xa[6] = f2bf(xhi.z); xa[7] = f2bf(xhi.w);

        // issue next-step x loads (in flight across the lgkm barrier)
        if (t + 1 < T_) {
            const float* xq = xp + (size_t)(t + 1) * E_;
            xlo = *(const float4*)(xq + 0);
            xhi = *(const float4*)(xq + 4);
        }

        // A fragments for h (4 k-tiles) from current buffer
        bf16x8 ah[4];
        #pragma unroll
        for (int kt = 0; kt < 4; kt++)
            ah[kt] = *(const bf16x8*)&h_lds[rsel + rbase + kt * 32];

        // 20 MFMAs
        f32x4 acc[4];
        #pragma unroll
        for (int gt = 0; gt < 4; gt++) acc[gt] = (f32x4)(0.0f);
        #pragma unroll
        for (int gt = 0; gt < 4; gt++)
            acc[gt] = __builtin_amdgcn_mfma_f32_16x16x32_bf16(xa, wfrag[gt][0], acc[gt], 0, 0, 0);
        #pragma unroll
        for (int kt = 0; kt < 4; kt++)
            #pragma unroll
            for (int gt = 0; gt < 4; gt++)
                acc[gt] = __builtin_amdgcn_mfma_f32_16x16x32_bf16(ah[kt], wfrag[gt][kt + 1], acc[gt], 0, 0, 0);

        // elementwise in C layout: reg r = batch row r (all lanes; dups in 16-63)
        float hn[4];
        #pragma unroll
        for (int r = 0; r < 4; r++) {
            float gi = acc[0][r] + bias0;
            float gf = acc[1][r] + bias1;
            float gg = acc[2][r] + bias2;
            float go = acc[3][r] + bias3;
            float i_ = fast_sigmoid(gi);
            float f_ = fast_sigmoid(gf);
            float g_ = fast_tanh(gg);
            float o_ = fast_sigmoid(go);
            float c_new = f_ * cr[r] + i_ * g_;
            float h_new = o_ * fast_tanh(c_new);
            int len = (r == 0) ? len0 : (r == 1) ? len1 : (r == 2) ? len2 : len3;
            bool m = (t < len);
            cr[r] = m ? c_new : cr[r];
            hr[r] = m ? h_new : hr[r];
            hn[r] = m ? h_new : 0.0f;
        }

        const int wsel = rsel ^ HBUF;
        if (lane < 16) {
            // store outputs (fire-and-forget) and write back h to next buffer
            #pragma unroll
            for (int r = 0; r < 4; r++) {
                out_base[(size_t)r * row_stride + (size_t)t * H_] = hn[r];
                h_lds[wsel + wbase + r * LROWH] = f2bf(hr[r]);
            }
        }
        rsel = wsel;
        LDS_BARRIER();
    }

    if (lane < 16) {
        #pragma unroll
        for (int r = 0; r < 4; r++) {
            h_out[(size_t)(row0 + r) * H_ + col16] = hr[r];
            c_out[(size_t)(row0 + r) * H_ + col16] = cr[r];
        }
    }
}

extern "C" void kernel_launch(void* const* d_in, const int* in_sizes, int n_in,
                              void* d_out, int out_size, void* d_ws, size_t ws_size,
                              hipStream_t stream) {
    const int*   obs_ids       = (const int*)d_in[0];
    const int*   obs_slot      = (const int*)d_in[1];
    const int*   action_ids    = (const int*)d_in[2];
    const int*   is_action     = (const int*)d_in[3];
    const int*   input_lengths = (const int*)d_in[4];
    const float* action_emb    = (const float*)d_in[5];
    const float* obs_emb       = (const float*)d_in[6];
    const float* W_ih          = (const float*)d_in[7];
    const float* W_hh          = (const float*)d_in[8];
    const float* b_ih          = (const float*)d_in[9];
    const float* b_hh          = (const float*)d_in[10];

    float* out      = (float*)d_out;
    float* outputs  = out;                                   // [B,T,H]
    float* h_out    = out + (size_t)B_ * T_ * H_;            // [1,B,H]
    float* c_out    = h_out + (size_t)B_ * H_;               // [1,B,H]
    float* embedded = c_out + (size_t)B_ * H_;               // [B,T,E]

    hipLaunchKernelGGL(embed_kernel, dim3((B_ * T_ + 255) / 256), dim3(256), 0, stream,
                       obs_ids, obs_slot, action_ids, is_action, action_emb, obs_emb, embedded);

    hipLaunchKernelGGL(lstm_kernel, dim3(NBLK), dim3(THREADS), 0, stream,
                       embedded, input_lengths, W_ih, W_hh, b_ih, b_hh,
                       outputs, h_out, c_out);
}

// Round 4
// 576.269 us; speedup vs baseline: 1.9460x; 1.9460x over previous
//
#include <hip/hip_runtime.h>

#define B_ 256
#define T_ 1024
#define E_ 32
#define H_ 128
#define NOBS_ 1048576
#define RPB 4                 // batch rows per LSTM block
#define NBLK (B_ / RPB)       // 64
#define NW 8                  // waves per block
#define THREADS (NW * 64)     // 512

#define LROWH 144             // h row stride in shorts (288B) -> row shift = 8 banks
#define HBUF (4 * LROWH)      // one h buffer (4 rows) in shorts

#define L2E 1.4426950408889634f

typedef __attribute__((ext_vector_type(8))) short bf16x8;
typedef __attribute__((ext_vector_type(4))) float f32x4;
typedef __attribute__((ext_vector_type(4))) int   i32x4;

// LDS-only barrier: drains LDS ops only; global loads/stores stay in flight.
#define LDS_BARRIER() asm volatile("s_waitcnt lgkmcnt(0)\n\ts_barrier" ::: "memory")

__device__ __forceinline__ short f2bf(float x) {
    unsigned u = __float_as_uint(x);
    unsigned r = u + 0x7FFFu + ((u >> 16) & 1u);   // RNE
    return (short)(r >> 16);
}

// ---------------- embedding kernel ----------------
__global__ void embed_kernel(const int* __restrict__ obs_ids,
                             const int* __restrict__ obs_slot,
                             const int* __restrict__ action_ids,
                             const int* __restrict__ is_action,
                             const float* __restrict__ action_emb,
                             const float* __restrict__ obs_emb,
                             float* __restrict__ embedded) {
    __shared__ float s_act[5 * E_];
    __shared__ float s_obs[11 * E_];
    for (int i = threadIdx.x; i < 5 * E_; i += blockDim.x) s_act[i] = action_emb[i];
    for (int i = threadIdx.x; i < 11 * E_; i += blockDim.x) s_obs[i] = obs_emb[i];
    __syncthreads();

    int s = blockIdx.x * blockDim.x + threadIdx.x;
    if (s >= B_ * T_) return;

    float acc[E_];
    if (is_action[s]) {
        int a = action_ids[s];
        #pragma unroll
        for (int e = 0; e < E_; e++) acc[e] = s_act[a * E_ + e];
    } else {
        #pragma unroll
        for (int e = 0; e < E_; e++) acc[e] = 0.0f;
        int lo = 0, hi = NOBS_;
        while (lo < hi) {
            int mid = (lo + hi) >> 1;
            if (obs_slot[mid] < s) lo = mid + 1; else hi = mid;
        }
        int j = lo;
        while (j < NOBS_ && obs_slot[j] == s) {
            int id = obs_ids[j];
            #pragma unroll
            for (int e = 0; e < E_; e++) acc[e] += s_obs[id * E_ + e];
            j++;
        }
    }
    float4* dst = (float4*)(embedded + (size_t)s * E_);
    #pragma unroll
    for (int q = 0; q < E_ / 4; q++) {
        float4 v; v.x = acc[4*q]; v.y = acc[4*q+1]; v.z = acc[4*q+2]; v.w = acc[4*q+3];
        dst[q] = v;
    }
}

// ---------------- LSTM kernel ----------------
// A-rows = (lane&15)>>2: each batch row duplicated x4 in M, so C rows 4g..4g+3
// all hold batch g = lane>>4. acc[gt][0] IS this lane's (row=lane>>4, col=lane&15)
// gate value -> dense elementwise, no cross-lane moves, no gate LDS.
// Weights/biases pre-scaled by log2(e) (2*log2(e) for g-gate) so activation
// uses raw exp2. Bias rides in as the MFMA C operand. One lgkm barrier/step.
__launch_bounds__(THREADS, 2)
__global__ void lstm_kernel(const float* __restrict__ embedded,
                            const int* __restrict__ lengths,
                            const float* __restrict__ W_ih,
                            const float* __restrict__ W_hh,
                            const float* __restrict__ b_ih,
                            const float* __restrict__ b_hh,
                            float* __restrict__ outputs,
                            float* __restrict__ h_out,
                            float* __restrict__ c_out) {
    __shared__ __align__(16) short h_lds[2 * HBUF];   // double-buffered [4][LROWH]

    const int tid  = threadIdx.x;
    const int lane = tid & 63;
    const int wave = tid >> 6;
    const int row0 = blockIdx.x * RPB;

    const int col16 = (wave << 4) + (lane & 15);   // this lane's gate/h column
    const int kgrp  = (lane >> 4) * 8;             // k-slice within K=32 tile
    const int brow  = (lane & 15) >> 2;            // A-operand batch row (dup x4)
    const int g     = lane >> 4;                   // batch row this lane OWNS in C

    // ---- persistent weight fragments (B operand), scaled by log2e ----
    bf16x8 wfrag[4][5];
    f32x4  biasv[4];
    #pragma unroll
    for (int gt = 0; gt < 4; gt++) {
        const float scale = (gt == 2) ? (2.0f * L2E) : L2E;
        int gcol = gt * H_ + col16;
        {
            const float* p = W_ih + (size_t)gcol * E_ + kgrp;
            bf16x8 v;
            #pragma unroll
            for (int j = 0; j < 8; j++) v[j] = f2bf(p[j] * scale);
            wfrag[gt][0] = v;
        }
        #pragma unroll
        for (int kt = 1; kt < 5; kt++) {
            const float* q = W_hh + (size_t)gcol * H_ + (kt - 1) * 32 + kgrp;
            bf16x8 v;
            #pragma unroll
            for (int j = 0; j < 8; j++) v[j] = f2bf(q[j] * scale);
            wfrag[gt][kt] = v;
        }
        float bv = (b_ih[gcol] + b_hh[gcol]) * scale;
        biasv[gt] = (f32x4)(bv);
    }

    const int len = lengths[row0 + g];
    float cr = 0.0f, hr = 0.0f;

    // x source for this lane's A fragment rows
    const float* xp = embedded + ((size_t)(row0 + brow) * T_) * E_ + kgrp;

    const int rbase = brow * LROWH + kgrp;         // A h-read base (shorts)
    const int wofs  = g * LROWH + col16;           // h write slot (shorts)
    float* const out_base = outputs + (size_t)(row0 + g) * T_ * H_ + col16;

    // zero both h buffers
    for (int i = tid; i < 2 * HBUF; i += THREADS) h_lds[i] = 0;
    __syncthreads();

    float4 xAlo = *(const float4*)(xp + 0 * E_);
    float4 xAhi = *(const float4*)(xp + 0 * E_ + 4);
    float4 xBlo = *(const float4*)(xp + 1 * E_);
    float4 xBhi = *(const float4*)(xp + 1 * E_ + 4);

    auto step = [&](int t, int RD, int WR, float4& xlo, float4& xhi, bool PF) {
        // A fragments for h from current buffer (<=2-way banks: free)
        bf16x8 ah[4];
        #pragma unroll
        for (int kt = 0; kt < 4; kt++)
            ah[kt] = *(const bf16x8*)&h_lds[RD + rbase + kt * 32];

        // pack current x -> bf16 A fragment (vmcnt wait lands here)
        int x0, x1, x2, x3;
        asm("v_cvt_pk_bf16_f32 %0, %1, %2" : "=v"(x0) : "v"(xlo.x), "v"(xlo.y));
        asm("v_cvt_pk_bf16_f32 %0, %1, %2" : "=v"(x1) : "v"(xlo.z), "v"(xlo.w));
        asm("v_cvt_pk_bf16_f32 %0, %1, %2" : "=v"(x2) : "v"(xhi.x), "v"(xhi.y));
        asm("v_cvt_pk_bf16_f32 %0, %1, %2" : "=v"(x3) : "v"(xhi.z), "v"(xhi.w));
        i32x4 xi; xi[0] = x0; xi[1] = x1; xi[2] = x2; xi[3] = x3;
        bf16x8 xa = __builtin_bit_cast(bf16x8, xi);

        // prefetch x(t+2) into the same buffer (in flight across barrier)
        if (PF) {
            const float* xq = xp + (size_t)(t + 2) * E_;
            xlo = *(const float4*)(xq + 0);
            xhi = *(const float4*)(xq + 4);
        }

        // 20 MFMAs; bias enters as C operand of the first one
        f32x4 acc[4];
        #pragma unroll
        for (int gt = 0; gt < 4; gt++)
            acc[gt] = __builtin_amdgcn_mfma_f32_16x16x32_bf16(xa, wfrag[gt][0], biasv[gt], 0, 0, 0);
        #pragma unroll
        for (int kt = 0; kt < 4; kt++)
            #pragma unroll
            for (int gt = 0; gt < 4; gt++)
                acc[gt] = __builtin_amdgcn_mfma_f32_16x16x32_bf16(ah[kt], wfrag[gt][kt + 1], acc[gt], 0, 0, 0);

        // dense elementwise: this lane owns (row g, col col16) = acc[.][0]
        float i_ = __builtin_amdgcn_rcpf(1.0f + exp2f(-acc[0][0]));
        float f_ = __builtin_amdgcn_rcpf(1.0f + exp2f(-acc[1][0]));
        float g_ = 1.0f - 2.0f * __builtin_amdgcn_rcpf(exp2f(acc[2][0]) + 1.0f);
        float o_ = __builtin_amdgcn_rcpf(1.0f + exp2f(-acc[3][0]));
        float c_new = f_ * cr + i_ * g_;
        float th = 1.0f - 2.0f * __builtin_amdgcn_rcpf(exp2f((2.0f * L2E) * c_new) + 1.0f);
        float h_new = o_ * th;
        bool m = (t < len);
        cr = m ? c_new : cr;
        hr = m ? h_new : hr;
        out_base[(size_t)t * H_] = m ? h_new : 0.0f;   // fire-and-forget

        // write h back (bf16) to the other buffer; conflict-free pattern
        int hb;
        asm("v_cvt_pk_bf16_f32 %0, %1, %2" : "=v"(hb) : "v"(hr), "v"(hr));
        h_lds[WR + wofs] = (short)hb;

        LDS_BARRIER();
    };

    for (int t = 0; t < T_ - 2; t += 2) {
        step(t,     0,    HBUF, xAlo, xAhi, true);
        step(t + 1, HBUF, 0,    xBlo, xBhi, true);
    }
    step(T_ - 2, 0,    HBUF, xAlo, xAhi, false);
    step(T_ - 1, HBUF, 0,    xBlo, xBhi, false);

    h_out[(size_t)(row0 + g) * H_ + col16] = hr;
    c_out[(size_t)(row0 + g) * H_ + col16] = cr;
}

extern "C" void kernel_launch(void* const* d_in, const int* in_sizes, int n_in,
                              void* d_out, int out_size, void* d_ws, size_t ws_size,
                              hipStream_t stream) {
    const int*   obs_ids       = (const int*)d_in[0];
    const int*   obs_slot      = (const int*)d_in[1];
    const int*   action_ids    = (const int*)d_in[2];
    const int*   is_action     = (const int*)d_in[3];
    const int*   input_lengths = (const int*)d_in[4];
    const float* action_emb    = (const float*)d_in[5];
    const float* obs_emb       = (const float*)d_in[6];
    const float* W_ih          = (const float*)d_in[7];
    const float* W_hh          = (const float*)d_in[8];
    const float* b_ih          = (const float*)d_in[9];
    const float* b_hh          = (const float*)d_in[10];

    float* out      = (float*)d_out;
    float* outputs  = out;                                   // [B,T,H]
    float* h_out    = out + (size_t)B_ * T_ * H_;            // [1,B,H]
    float* c_out    = h_out + (size_t)B_ * H_;               // [1,B,H]
    float* embedded = c_out + (size_t)B_ * H_;               // [B,T,E]

    hipLaunchKernelGGL(embed_kernel, dim3((B_ * T_ + 255) / 256), dim3(256), 0, stream,
                       obs_ids, obs_slot, action_ids, is_action, action_emb, obs_emb, embedded);

    hipLaunchKernelGGL(lstm_kernel, dim3(NBLK), dim3(THREADS), 0, stream,
                       embedded, input_lengths, W_ih, W_hh, b_ih, b_hh,
                       outputs, h_out, c_out);
}